// Round 6
// baseline (107.438 us; speedup 1.0000x reference)
//
#include <hip/hip_runtime.h>

// DCNv2 fused, round 6: channels-last bf16 gather + MFMA, 4-wave blocks.
// B=8, Cin=Cout=128, H=W=Ho=Wo=64, kh=kw=3, stride=1, pad=1, dil=1.
//
// R5 -> R6: (1) 256-thr blocks, wave = 32co x 32p (B-LDS redundancy 8x -> 4x);
// (2) __launch_bounds__(256,4): 128-VGPR cap so the 32-VGPR gather prefetch
// stays in registers (R4/R5 risk: 64-cap sank the prefetch); (3) 16B-granule
// xor swizzle pg = gi ^ (row&7) -> uniform bank-group spread for both b128
// stage writes and B-frag reads; (4) grid 1024 x 4 waves = exactly 4
// blocks/CU, no tail.
//
// grid 1024 = (ph, ho, b): b = blk&7 (XCD swizzle), ho = (blk>>3)&63,
// ph = blk>>9. Block tile 128co x 32p; wave w: co 32w..32w+31.
// K-loop: 9 steps of K=128. Per step: convert+stage s_t[buf] -> barrier
// (nothing outstanding) -> A-frags (global, issued BEFORE gathers so the
// FIFO vmcnt wait for MFMA leaves gathers in flight) -> prefetch next
// gathers (8 dwordx4) -> 8 ds_read_b128 + 16 MFMA 16x16x32_bf16.

constexpr int CIN = 128, COUT = 128, H = 64, W = 64, KK = 9;
constexpr int HW = H * W;

typedef __attribute__((ext_vector_type(8))) short short8;
typedef __attribute__((ext_vector_type(4))) float float4v;

static __device__ __forceinline__ unsigned short f32_to_bf16_rne(float f) {
  unsigned u = __float_as_uint(f);
  return (unsigned short)((u + 0x7FFFu + ((u >> 16) & 1u)) >> 16);
}
static __device__ __forceinline__ float blo(unsigned u) {
  return __uint_as_float(u << 16);
}
static __device__ __forceinline__ float bhi(unsigned u) {
  return __uint_as_float(u & 0xFFFF0000u);
}

// ---- transpose prep: input[b][ci][y][x] f32 -> inT[b][y][x][ci] bf16 ----
__global__ __launch_bounds__(256) void tprep_kernel(
    const float* __restrict__ in, unsigned short* __restrict__ inT) {
  __shared__ unsigned short lt[64 * 130];  // [x][ci], pad 130
  const int b = blockIdx.x >> 6, y = blockIdx.x & 63;
  for (int i = threadIdx.x; i < 128 * 64; i += 256) {
    const int ci = i >> 6, x = i & 63;  // consecutive i -> consecutive x
    lt[x * 130 + ci] = f32_to_bf16_rne(in[((b * 128 + ci) * 64 + y) * 64 + x]);
  }
  __syncthreads();
  unsigned* outp = (unsigned*)inT + (size_t)(b * 64 + y) * 64 * 64;
  for (int i = threadIdx.x; i < 64 * 64; i += 256) {
    const int x = i >> 6, c2 = (i & 63) * 2;  // consecutive i -> consecutive ci
    outp[x * 64 + (i & 63)] =
        (unsigned)lt[x * 130 + c2] | ((unsigned)lt[x * 130 + c2 + 1] << 16);
  }
}

// ---- weight prep: w[co][ci][k] fp32 -> bf16 A-fragments ----
// wt[(k*4+ks)*8 + c16][lane][j]; value = w[co=c16*16+(lane&15)]
//                                         [ci=ks*32+(lane>>4)*8+j][k]
__global__ __launch_bounds__(256) void wprep_kernel(
    const float* __restrict__ w, unsigned short* __restrict__ wt) {
  const int t = blockIdx.x * 256 + threadIdx.x;
  if (t >= 9 * 4 * 8 * 64) return;
  const int lane = t & 63, c16 = (t >> 6) & 7, kt = t >> 9;
  const int ks = kt & 3, k = kt >> 2;
  const int co = c16 * 16 + (lane & 15);
  const int ci0 = ks * 32 + (lane >> 4) * 8;
  unsigned pk[4];
#pragma unroll
  for (int jj = 0; jj < 4; ++jj) {
    const unsigned short h0 =
        f32_to_bf16_rne(w[(co * CIN + ci0 + 2 * jj) * KK + k]);
    const unsigned short h1 =
        f32_to_bf16_rne(w[(co * CIN + ci0 + 2 * jj + 1) * KK + k]);
    pk[jj] = (unsigned)h0 | ((unsigned)h1 << 16);
  }
  *(uint4*)(wt + (size_t)t * 8) = make_uint4(pk[0], pk[1], pk[2], pk[3]);
}

__global__ __launch_bounds__(256, 4) void dcn_mfma_kernel(
    const unsigned short* __restrict__ inT, const float* __restrict__ offset,
    const float* __restrict__ mask, const unsigned short* __restrict__ wt,
    const float* __restrict__ bias, float* __restrict__ out) {
  __shared__ int2 pos_i[KK * 32];    // channels-last elem base: row0, row1
  __shared__ float4 pos_w[KK * 32];  // folded slot weights cA0,cB0,cA1,cB1
  __shared__ unsigned short s_t[2][32 * 128];  // dbuf [p][ci], xor-swizzled

  const int b = blockIdx.x & 7;  // XCD swizzle: batch b -> XCD b (L2 locality)
  const int ho = (blockIdx.x >> 3) & 63;
  const int ph = blockIdx.x >> 9;  // 0..1: p-half
  const int tid = threadIdx.x;

  // ---- Phase A: per-(k,p) tables; taps folded onto slots (bx, bx+1) ----
  for (int idx = tid; idx < KK * 32; idx += 256) {
    const int k = idx >> 5, p = idx & 31;
    const int pg = ph * 32 + p;
    const int ky = k / 3, kx = k - 3 * ky;
    const float py = (float)(ho - 1 + ky) +
                     offset[((b * 18 + 2 * k) * 64 + ho) * 64 + pg];
    const float px = (float)(pg - 1 + kx) +
                     offset[((b * 18 + 2 * k + 1) * 64 + ho) * 64 + pg];
    const float m = mask[((b * 9 + k) * 64 + ho) * 64 + pg];
    const float y0f = floorf(py), x0f = floorf(px);
    const int y0 = (int)y0f, x0 = (int)x0f;
    const float ly = py - y0f, lx = px - x0f;
    const float hy = 1.f - ly, hx = 1.f - lx;
    const bool vy0 = (y0 >= 0) && (y0 < H);
    const bool vy1 = (y0 + 1 >= 0) && (y0 + 1 < H);
    const bool vx0 = (x0 >= 0) && (x0 < W);
    const bool vx1 = (x0 + 1 >= 0) && (x0 + 1 < W);
    const float w00 = (vy0 && vx0) ? hy * hx * m : 0.f;
    const float w01 = (vy0 && vx1) ? hy * lx * m : 0.f;
    const float w10 = (vy1 && vx0) ? ly * hx * m : 0.f;
    const float w11 = (vy1 && vx1) ? ly * lx * m : 0.f;
    const int cy0 = min(max(y0, 0), H - 1), cy1 = min(max(y0 + 1, 0), H - 1);
    const int bx = min(max(x0, 0), W - 2);
    const int s0 = min(max(x0 - bx, 0), 1);
    const int s1 = min(max(x0 + 1 - bx, 0), 1);
    // exact fold: invalid taps weigh 0; shared slots add a zero term
    const float cA0 = (s0 == 0 ? w00 : 0.f) + (s1 == 0 ? w01 : 0.f);
    const float cB0 = (s0 == 1 ? w00 : 0.f) + (s1 == 1 ? w01 : 0.f);
    const float cA1 = (s0 == 0 ? w10 : 0.f) + (s1 == 0 ? w11 : 0.f);
    const float cB1 = (s0 == 1 ? w10 : 0.f) + (s1 == 1 ? w11 : 0.f);
    pos_i[idx] = make_int2((cy0 * 64 + bx) * 128, (cy1 * 64 + bx) * 128);
    pos_w[idx] = make_float4(cA0, cB0, cA1, cB1);
  }
  __syncthreads();

  const int wave = tid >> 6;  // 0..3 -> co block of 32
  const int lane = tid & 63;
  const int quad = lane >> 4, l15 = lane & 15;
  const int p_loc = tid >> 3;  // 0..31: staged p row
  const int cg8 = tid & 7;     // ci chunk of 16 (two 16B granules)

  float4v acc[2][2];  // [sub = co16][ns = p16]
#pragma unroll
  for (int s = 0; s < 2; ++s)
#pragma unroll
    for (int n = 0; n < 2; ++n) acc[s][n] = (float4v)(0.f);

  const unsigned short* inb = inT + (size_t)b * HW * 128;

  // prologue: table + gathers for k=0 (8 x dwordx4 = 32 VGPRs in flight)
  int2 P = pos_i[p_loc];
  float4 Wc = pos_w[p_loc];
  uint4 ga0, ga1, gb0, gb1, gc0, gc1, gd0, gd1;
  {
    const unsigned short* a0 = inb + P.x + cg8 * 16;
    const unsigned short* a1 = inb + P.y + cg8 * 16;
    ga0 = *(const uint4*)a0;
    ga1 = *(const uint4*)(a0 + 8);
    gb0 = *(const uint4*)(a0 + 128);
    gb1 = *(const uint4*)(a0 + 136);
    gc0 = *(const uint4*)a1;
    gc1 = *(const uint4*)(a1 + 8);
    gd0 = *(const uint4*)(a1 + 128);
    gd1 = *(const uint4*)(a1 + 136);
  }

  for (int k = 0; k < KK; ++k) {
    const int buf = k & 1;
    // ---- convert + stage: s[ci] = cA0*v00 + cB0*v01 + cA1*v10 + cB1*v11 ----
    {
      const uint4 A4[2] = {ga0, ga1}, B4[2] = {gb0, gb1};
      const uint4 C4[2] = {gc0, gc1}, D4[2] = {gd0, gd1};
#pragma unroll
      for (int h = 0; h < 2; ++h) {
        const unsigned u00[4] = {A4[h].x, A4[h].y, A4[h].z, A4[h].w};
        const unsigned u01[4] = {B4[h].x, B4[h].y, B4[h].z, B4[h].w};
        const unsigned u10[4] = {C4[h].x, C4[h].y, C4[h].z, C4[h].w};
        const unsigned u11[4] = {D4[h].x, D4[h].y, D4[h].z, D4[h].w};
        unsigned pk[4];
#pragma unroll
        for (int j = 0; j < 4; ++j) {
          const float se = Wc.x * blo(u00[j]) + Wc.y * blo(u01[j]) +
                           Wc.z * blo(u10[j]) + Wc.w * blo(u11[j]);
          const float so = Wc.x * bhi(u00[j]) + Wc.y * bhi(u01[j]) +
                           Wc.z * bhi(u10[j]) + Wc.w * bhi(u11[j]);
          pk[j] = (unsigned)f32_to_bf16_rne(se) |
                  ((unsigned)f32_to_bf16_rne(so) << 16);
        }
        const int gi = cg8 * 2 + h;              // logical 16B granule
        const int pgr = gi ^ (p_loc & 7);        // xor swizzle
        *(uint4*)&s_t[buf][p_loc * 128 + pgr * 8] =
            make_uint4(pk[0], pk[1], pk[2], pk[3]);
      }
    }
    __syncthreads();  // nothing outstanding here: drain is free

    // ---- A-frags FIRST (FIFO vmcnt: MFMA wait leaves gathers in flight) ----
    short8 A[4][2];  // [ks][sub]
    {
      const unsigned short* wk =
          wt + ((size_t)(k * 4) * 8 + wave * 2) * 512 + (size_t)lane * 8;
#pragma unroll
      for (int ks = 0; ks < 4; ++ks) {
        A[ks][0] = *(const short8*)(wk + (size_t)ks * 8 * 512);
        A[ks][1] = *(const short8*)(wk + (size_t)ks * 8 * 512 + 512);
      }
    }

    // ---- prefetch next k's gathers (hidden under ds_read + MFMA) ----
    if (k < KK - 1) {
      P = pos_i[(k + 1) * 32 + p_loc];
      Wc = pos_w[(k + 1) * 32 + p_loc];
      const unsigned short* a0 = inb + P.x + cg8 * 16;
      const unsigned short* a1 = inb + P.y + cg8 * 16;
      ga0 = *(const uint4*)a0;
      ga1 = *(const uint4*)(a0 + 8);
      gb0 = *(const uint4*)(a0 + 128);
      gb1 = *(const uint4*)(a0 + 136);
      gc0 = *(const uint4*)a1;
      gc1 = *(const uint4*)(a1 + 8);
      gd0 = *(const uint4*)(a1 + 128);
      gd1 = *(const uint4*)(a1 + 136);
    }

    // ---- B ds_reads (xor-swizzled) + 16 MFMA ----
#pragma unroll
    for (int ks = 0; ks < 4; ++ks) {
      const int gi = ks * 4 + quad;
      const int o0 = l15 * 128 + (gi ^ (l15 & 7)) * 8;          // ns=0 row=l15
      const int o1 = (16 + l15) * 128 + (gi ^ (l15 & 7)) * 8;   // ns=1
      const short8 b0 = *(const short8*)&s_t[buf][o0];
      const short8 b1 = *(const short8*)&s_t[buf][o1];
      acc[0][0] =
          __builtin_amdgcn_mfma_f32_16x16x32_bf16(A[ks][0], b0, acc[0][0], 0, 0, 0);
      acc[0][1] =
          __builtin_amdgcn_mfma_f32_16x16x32_bf16(A[ks][0], b1, acc[0][1], 0, 0, 0);
      acc[1][0] =
          __builtin_amdgcn_mfma_f32_16x16x32_bf16(A[ks][1], b0, acc[1][0], 0, 0, 0);
      acc[1][1] =
          __builtin_amdgcn_mfma_f32_16x16x32_bf16(A[ks][1], b1, acc[1][1], 0, 0, 0);
    }
  }

  // ---- epilogue: C/D layout col(N=p)=lane&15, row(M=co)=quad*4+reg ----
#pragma unroll
  for (int sub = 0; sub < 2; ++sub) {
#pragma unroll
    for (int r = 0; r < 4; ++r) {
      const int co = wave * 32 + sub * 16 + quad * 4 + r;
      const float bb = bias[co];
      float* op = out + ((size_t)(b * COUT + co) * H + ho) * W + ph * 32;
      op[l15] = acc[sub][0][r] + bb;       // ns=0
      op[16 + l15] = acc[sub][1][r] + bb;  // ns=1
    }
  }
}

// ---- fallback (ws too small): round-1 fp32 kernel ----
__global__ __launch_bounds__(256) void dcn_fp32_kernel(
    const float* __restrict__ input, const float* __restrict__ offset,
    const float* __restrict__ mask, const float* __restrict__ weight,
    const float* __restrict__ bias, float* __restrict__ out) {
  __shared__ short4 pos_o[KK * 64];
  __shared__ float4 pos_w[KK * 64];
  __shared__ float s_tile[64 * 64];
  __shared__ float w_tile[64 * 128];
  const int b = blockIdx.x >> 6;
  const int ho = blockIdx.x & 63;
  const int tid = threadIdx.x;
  for (int idx = tid; idx < KK * 64; idx += 256) {
    const int k = idx >> 6, pp = idx & 63;
    const int ky = k / 3, kx = k - 3 * ky;
    const float py = (float)(ho - 1 + ky) +
                     offset[((b * 18 + 2 * k) * 64 + ho) * 64 + pp];
    const float px = (float)(pp - 1 + kx) +
                     offset[((b * 18 + 2 * k + 1) * 64 + ho) * 64 + pp];
    const float m = mask[((b * 9 + k) * 64 + ho) * 64 + pp];
    const float y0f = floorf(py), x0f = floorf(px);
    const int y0 = (int)y0f, x0 = (int)x0f;
    const float ly = py - y0f, lx = px - x0f;
    const float hy = 1.f - ly, hx = 1.f - lx;
    const bool vy0 = (y0 >= 0) && (y0 < H), vy1 = (y0 + 1 >= 0) && (y0 + 1 < H);
    const bool vx0 = (x0 >= 0) && (x0 < W), vx1 = (x0 + 1 >= 0) && (x0 + 1 < W);
    const int cy0 = min(max(y0, 0), H - 1), cy1 = min(max(y0 + 1, 0), H - 1);
    const int cx0 = min(max(x0, 0), W - 1), cx1 = min(max(x0 + 1, 0), W - 1);
    pos_o[idx] = make_short4((short)(cy0 * W + cx0), (short)(cy0 * W + cx1),
                             (short)(cy1 * W + cx0), (short)(cy1 * W + cx1));
    pos_w[idx] = make_float4((vy0 && vx0) ? hy * hx * m : 0.f,
                             (vy0 && vx1) ? hy * lx * m : 0.f,
                             (vy1 && vx0) ? ly * hx * m : 0.f,
                             (vy1 && vx1) ? ly * lx * m : 0.f);
  }
  const int cog = tid >> 4, pg = tid & 15;
  float acc[8][4];
#pragma unroll
  for (int j = 0; j < 8; ++j)
#pragma unroll
    for (int q = 0; q < 4; ++q) acc[j][q] = 0.f;
  const float* inp_b = input + (size_t)b * CIN * HW;
  for (int k = 0; k < KK; ++k) {
    for (int cc = 0; cc < 2; ++cc) {
      __syncthreads();
      for (int i = tid; i < 64 * 64; i += 256) {
        const int cil = i >> 6, pp = i & 63;
        const float* plane = inp_b + (size_t)(cc * 64 + cil) * HW;
        const short4 o = pos_o[k * 64 + pp];
        const float4 w = pos_w[k * 64 + pp];
        s_tile[i] = w.x * plane[(int)o.x] + w.y * plane[(int)o.y] +
                    w.z * plane[(int)o.z] + w.w * plane[(int)o.w];
      }
      for (int i = tid; i < 64 * 128; i += 256) {
        const int cil = i & 63, co = i >> 6;
        w_tile[cil * 128 + co] = weight[(co * CIN + cc * 64 + cil) * KK + k];
      }
      __syncthreads();
#pragma unroll 8
      for (int cil = 0; cil < 64; ++cil) {
        const float4 sv = *(const float4*)&s_tile[cil * 64 + (pg << 2)];
        const float4 wa = *(const float4*)&w_tile[cil * 128 + (cog << 3)];
        const float4 wb = *(const float4*)&w_tile[cil * 128 + (cog << 3) + 4];
        const float s4[4] = {sv.x, sv.y, sv.z, sv.w};
        const float w8[8] = {wa.x, wa.y, wa.z, wa.w, wb.x, wb.y, wb.z, wb.w};
#pragma unroll
        for (int j = 0; j < 8; ++j)
#pragma unroll
          for (int q = 0; q < 4; ++q) acc[j][q] = fmaf(w8[j], s4[q], acc[j][q]);
      }
    }
  }
  float* outp = out + (size_t)b * COUT * HW + ho * W;
#pragma unroll
  for (int j = 0; j < 8; ++j) {
    const int co = (cog << 3) + j;
    const float bb = bias[co];
    *(float4*)&outp[co * HW + (pg << 2)] =
        make_float4(acc[j][0] + bb, acc[j][1] + bb, acc[j][2] + bb,
                    acc[j][3] + bb);
  }
}

extern "C" void kernel_launch(void* const* d_in, const int* in_sizes, int n_in,
                              void* d_out, int out_size, void* d_ws,
                              size_t ws_size, hipStream_t stream) {
  const float* input = (const float*)d_in[0];
  const float* offset = (const float*)d_in[1];
  const float* mask = (const float*)d_in[2];
  const float* weight = (const float*)d_in[3];
  const float* bias = (const float*)d_in[4];
  float* out = (float*)d_out;

  const size_t wt_bytes = (size_t)9 * 4 * 8 * 64 * 8 * 2;  // 294912
  const size_t inT_bytes = (size_t)8 * HW * 128 * 2;       // 8388608
  if (ws_size >= wt_bytes + inT_bytes) {
    unsigned short* wt = (unsigned short*)d_ws;
    unsigned short* inT = (unsigned short*)((char*)d_ws + wt_bytes);
    hipLaunchKernelGGL(wprep_kernel, dim3(72), dim3(256), 0, stream, weight, wt);
    hipLaunchKernelGGL(tprep_kernel, dim3(512), dim3(256), 0, stream, input, inT);
    hipLaunchKernelGGL(dcn_mfma_kernel, dim3(1024), dim3(256), 0, stream, inT,
                       offset, mask, wt, bias, out);
  } else {
    hipLaunchKernelGGL(dcn_fp32_kernel, dim3(512), dim3(256), 0, stream, input,
                       offset, mask, weight, bias, out);
  }
}